// Round 2
// baseline (683.280 us; speedup 1.0000x reference)
//
#include <hip/hip_runtime.h>

typedef __attribute__((ext_vector_type(4))) _Float16 f16x4;
typedef __attribute__((ext_vector_type(4))) float f32x4;

#define NB 4096
#define TT 200
#define DD 64
#define H0 128
#define H1 64
#define MP 76    // MhT row pitch in halfs: 152B = 38 dwords, stride mod 32 = 6 -> conflict-free
#define WP 140   // W1T row pitch in halfs: 280B = 70 dwords, stride mod 32 = 6 -> conflict-free

// Transposed-GEMM DIN attention. Per block b:
//   M_b = W0b - W0c + diag(q) W0d   (64x128, fp16 in LDS as [h][d])
//   cb  = b0 + q@(W0a + W0c)        (hi/lo folded into MhT cols 64/65)
//   layer0^T: h0t = M_b^T @ k^T  -> D-fragment == layer1 B-fragment (no LDS round trip)
//   layer1^T: h1t = W1^T @ h0t   (b1 hi/lo folded into W1T cols 128/129)
//   logit/softmax/pool in fp32. Activations hi/lo fp16 split for error compensation.
__global__ __launch_bounds__(256, 4)
void din_attn(const float* __restrict__ q, const float* __restrict__ k,
              const float* __restrict__ v, const int* __restrict__ mask,
              const float* __restrict__ W0, const float* __restrict__ b0,
              const float* __restrict__ W1, const float* __restrict__ b1,
              const float* __restrict__ Wf, float* __restrict__ out)
{
  const int b    = blockIdx.x;
  const int tid  = threadIdx.x;
  const int lane = tid & 63;
  const int wid  = tid >> 6;
  const int r16  = lane & 15;   // t-col within strip (and A-row select)
  const int g4   = lane >> 4;   // k-subgroup / D row-group

  __shared__ __align__(16) _Float16 MhT[H0 * MP];
  __shared__ __align__(16) _Float16 W1T[H1 * WP];
  __shared__ float scratch[280];   // cb partials (256) -> reuse: owav[4][68] + msh[4] + ssh[4]

  const float* qb = q + b * DD;
  const float* kb = k + (size_t)b * TT * DD;
  const float* vb = v + (size_t)b * TT * DD;
  const int*   mb = mask + b * TT;

  // ---- prologue: cb partials (all 256 threads) ----
  {
    int h = tid & 127, half = tid >> 7;
    float s = 0.f;
    #pragma unroll 8
    for (int i = 0; i < 32; ++i) {
      int d = half * 32 + i;
      s += qb[d] * (W0[d * H0 + h] + W0[(128 + d) * H0 + h]);
    }
    scratch[tid] = s;
  }
  // M_b^T -> LDS (fp16, [h][d])
  #pragma unroll 4
  for (int i = 0; i < 32; ++i) {
    int idx = i * 256 + tid;
    int h = idx & 127, d = idx >> 7;
    float val = W0[(64 + d) * H0 + h] - W0[(128 + d) * H0 + h]
              + qb[d] * W0[(192 + d) * H0 + h];
    MhT[h * MP + d] = (_Float16)val;
  }
  // W1^T -> LDS (fp16, [j][h])
  #pragma unroll 4
  for (int i = 0; i < 32; ++i) {
    int idx = i * 256 + tid;
    int hh = idx >> 6, j = idx & 63;
    W1T[j * WP + hh] = (_Float16)W1[idx];
  }
  __syncthreads();
  if (tid < H0) {
    float cbv = scratch[tid] + scratch[tid + 128] + b0[tid];
    _Float16 chi = (_Float16)cbv;
    MhT[tid * MP + 64] = chi;
    MhT[tid * MP + 65] = (_Float16)(cbv - (float)chi);
  }
  if (tid < H1) {
    float bb = b1[tid];
    _Float16 bh = (_Float16)bb;
    W1T[tid * WP + 128] = bh;
    W1T[tid * WP + 129] = (_Float16)(bb - (float)bh);
  }
  __syncthreads();

  float wfv[4][4];
  #pragma unroll
  for (int c1 = 0; c1 < 4; ++c1) {
    float4 w4 = *(const float4*)(Wf + c1 * 16 + 4 * g4);
    wfv[c1][0] = w4.x; wfv[c1][1] = w4.y; wfv[c1][2] = w4.z; wfv[c1][3] = w4.w;
  }

  float m_run = -1e30f, s_run = 0.f, o_run = 0.f;

  for (int s = wid; s < 13; s += 4) {
    const int t0   = s * 16;
    const int trow = t0 + r16;
    const bool tv  = trow < TT;

    int mm = tv ? mb[trow] : -1;

    // k^T B-fragments straight from global; v stream issued early
    float4 kq[4];
    #pragma unroll
    for (int ks = 0; ks < 4; ++ks) {
      float4 z = {0.f, 0.f, 0.f, 0.f};
      kq[ks] = tv ? *(const float4*)(kb + trow * DD + ks * 16 + 4 * g4) : z;
    }
    float vv[16];
    #pragma unroll
    for (int i = 0; i < 16; ++i) {
      int t = t0 + i;
      vv[i] = (t < TT) ? vb[t * DD + lane] : 0.f;
    }

    // hi/lo split of k (B operand)
    f16x4 bhi[4], blo[4];
    #pragma unroll
    for (int ks = 0; ks < 4; ++ks) {
      float kf[4] = {kq[ks].x, kq[ks].y, kq[ks].z, kq[ks].w};
      #pragma unroll
      for (int j = 0; j < 4; ++j) {
        _Float16 hi = (_Float16)kf[j];
        bhi[ks][j] = hi;
        blo[ks][j] = (_Float16)(kf[j] - (float)hi);
      }
    }
    // constant-1 B fragment for the bias K-rows (valid t cols only)
    f16x4 bONE = {(_Float16)0.f, (_Float16)0.f, (_Float16)0.f, (_Float16)0.f};
    if (g4 == 0 && tv) { bONE[0] = (_Float16)1.f; bONE[1] = (_Float16)1.f; }

    // ---- layer0^T: h0t[h=c*16+4g4+r][t=t0+r16], bias folded, relu, hi/lo split ----
    f16x4 hhi[8], hlo[8];
    #pragma unroll
    for (int c = 0; c < 8; ++c) {
      const _Float16* mrow = &MhT[(c * 16 + r16) * MP];
      f32x4 acc = {0.f, 0.f, 0.f, 0.f};
      #pragma unroll
      for (int ks = 0; ks < 4; ++ks) {
        f16x4 af = *(const f16x4*)(mrow + ks * 16 + 4 * g4);
        acc = __builtin_amdgcn_mfma_f32_16x16x16f16(af, bhi[ks], acc, 0, 0, 0);
        acc = __builtin_amdgcn_mfma_f32_16x16x16f16(af, blo[ks], acc, 0, 0, 0);
      }
      f16x4 ab = {(_Float16)0.f, (_Float16)0.f, (_Float16)0.f, (_Float16)0.f};
      if (g4 == 0) { ab[0] = mrow[64]; ab[1] = mrow[65]; }
      acc = __builtin_amdgcn_mfma_f32_16x16x16f16(ab, bONE, acc, 0, 0, 0);
      #pragma unroll
      for (int r = 0; r < 4; ++r) {
        float hv = acc[r] > 0.f ? acc[r] : 0.f;
        _Float16 hi = (_Float16)hv;
        hhi[c][r] = hi;
        hlo[c][r] = (_Float16)(hv - (float)hi);
      }
    }

    // ---- layer1^T + logit: h1t[j=c1*16+4g4+r][t], b1 folded ----
    float p = 0.f;
    #pragma unroll
    for (int c1 = 0; c1 < 4; ++c1) {
      const _Float16* wrow = &W1T[(c1 * 16 + r16) * WP];
      f32x4 acc = {0.f, 0.f, 0.f, 0.f};
      #pragma unroll
      for (int ks = 0; ks < 8; ++ks) {
        f16x4 af = *(const f16x4*)(wrow + ks * 16 + 4 * g4);
        acc = __builtin_amdgcn_mfma_f32_16x16x16f16(af, hhi[ks], acc, 0, 0, 0);
        acc = __builtin_amdgcn_mfma_f32_16x16x16f16(af, hlo[ks], acc, 0, 0, 0);
      }
      f16x4 ab = {(_Float16)0.f, (_Float16)0.f, (_Float16)0.f, (_Float16)0.f};
      if (g4 == 0) { ab[0] = wrow[128]; ab[1] = wrow[129]; }
      acc = __builtin_amdgcn_mfma_f32_16x16x16f16(ab, bONE, acc, 0, 0, 0);
      #pragma unroll
      for (int r = 0; r < 4; ++r) {
        float h1 = acc[r] > 0.f ? acc[r] : 0.f;
        p = fmaf(h1, wfv[c1][r], p);
      }
    }

    // reduce logit over the 4 g4 replicas (same t-col)
    p += __shfl_xor(p, 16, 64);
    p += __shfl_xor(p, 32, 64);
    // mask: keep / masked(-1e30) / pad(-2e30)
    p = (mm == 1) ? p : (mm == 0 ? -1e30f : -2e30f);

    // gather the strip's 16 logits to every lane
    float lt[16];
    #pragma unroll
    for (int i = 0; i < 16; ++i) lt[i] = __shfl(p, i, 64);

    // online softmax update + v pooling (d = lane)
    float m_new = m_run;
    #pragma unroll
    for (int i = 0; i < 16; ++i) m_new = fmaxf(m_new, lt[i]);
    float scale = __expf(m_run - m_new);
    float e[16];
    float esum = 0.f;
    #pragma unroll
    for (int i = 0; i < 16; ++i) { e[i] = __expf(lt[i] - m_new); esum += e[i]; }
    s_run = s_run * scale + esum;
    o_run *= scale;
    #pragma unroll
    for (int i = 0; i < 16; ++i) o_run = fmaf(e[i], vv[i], o_run);
    m_run = m_new;
  }

  // ---- cross-wave flash combine (scratch reused: owav[4][68] @0, msh @272, ssh @276) ----
  scratch[wid * 68 + lane] = o_run;
  if (lane == 0) { scratch[272 + wid] = m_run; scratch[276 + wid] = s_run; }
  __syncthreads();

  if (tid < DD) {
    float mstar = fmaxf(fmaxf(scratch[272], scratch[273]),
                        fmaxf(scratch[274], scratch[275]));
    float acc = 0.f, ssum = 0.f;
    #pragma unroll
    for (int w = 0; w < 4; ++w) {
      float f = __expf(scratch[272 + w] - mstar);
      acc  += scratch[w * 68 + tid] * f;
      ssum += scratch[276 + w] * f;
    }
    out[b * DD + tid] = acc / ssum;
  }
}

extern "C" void kernel_launch(void* const* d_in, const int* in_sizes, int n_in,
                              void* d_out, int out_size, void* d_ws, size_t ws_size,
                              hipStream_t stream) {
  const float* q    = (const float*)d_in[0];
  const float* k    = (const float*)d_in[1];
  const float* v    = (const float*)d_in[2];
  const int*   mask = (const int*)d_in[3];
  const float* W0   = (const float*)d_in[4];
  const float* b0   = (const float*)d_in[5];
  const float* W1   = (const float*)d_in[6];
  const float* b1   = (const float*)d_in[7];
  const float* Wf   = (const float*)d_in[8];
  float* out = (float*)d_out;
  din_attn<<<dim3(NB), dim3(256), 0, stream>>>(q, k, v, mask, W0, b0, W1, b1, Wf, out);
}

// Round 3
// 260.346 us; speedup vs baseline: 2.6245x; 2.6245x over previous
//
#include <hip/hip_runtime.h>

typedef __attribute__((ext_vector_type(4))) _Float16 f16x4;
typedef __attribute__((ext_vector_type(4))) float f32x4;

#define NB 4096
#define TT 200
#define DD 64
#define H0 128
#define H1 64
#define MP 76    // MhT row pitch in halfs: 152B = 38 dwords, stride mod 32 = 6 -> conflict-free
#define WP 140   // W1T row pitch in halfs: 280B = 70 dwords, stride mod 32 = 6 -> conflict-free

// Transposed-GEMM DIN attention. Per block b:
//   M_b = W0b - W0c + diag(q) W0d   (64x128, fp16 in LDS as [h][d])
//   cb  = b0 + q@(W0a + W0c)        (hi/lo folded into MhT cols 64/65)
//   layer0^T: h0t = M_b^T @ k^T  -> D-fragment == layer1 B-fragment (no LDS round trip)
//   layer1^T: h1t = W1^T @ h0t   (b1 hi/lo folded into W1T cols 128/129)
//   logit/softmax/pool in fp32. Activations hi/lo fp16 split for error compensation.
// launch_bounds (256,2): (256,4) made the compiler split 64 arch + 64 accum VGPRs
// and spill ~1.5 GB/dispatch to scratch (R2). At (256,2) allocation is ~96-112
// VGPRs, and the 39 KB LDS footprint still yields 4 blocks/CU.
__global__ __launch_bounds__(256, 2)
void din_attn(const float* __restrict__ q, const float* __restrict__ k,
              const float* __restrict__ v, const int* __restrict__ mask,
              const float* __restrict__ W0, const float* __restrict__ b0,
              const float* __restrict__ W1, const float* __restrict__ b1,
              const float* __restrict__ Wf, float* __restrict__ out)
{
  const int b    = blockIdx.x;
  const int tid  = threadIdx.x;
  const int lane = tid & 63;
  const int wid  = tid >> 6;
  const int r16  = lane & 15;   // t-col within strip (and A-row select)
  const int g4   = lane >> 4;   // k-subgroup / D row-group

  __shared__ __align__(16) _Float16 MhT[H0 * MP];
  __shared__ __align__(16) _Float16 W1T[H1 * WP];
  __shared__ __align__(16) float WfS[DD];
  __shared__ float scratch[280];   // cb partials (256) -> reuse: owav[4][68] + msh[4] + ssh[4]

  const float* qb = q + b * DD;
  const float* kb = k + (size_t)b * TT * DD;
  const float* vb = v + (size_t)b * TT * DD;
  const int*   mb = mask + b * TT;

  // ---- prologue: cb partials (all 256 threads) ----
  {
    int h = tid & 127, half = tid >> 7;
    float s = 0.f;
    #pragma unroll 8
    for (int i = 0; i < 32; ++i) {
      int d = half * 32 + i;
      s += qb[d] * (W0[d * H0 + h] + W0[(128 + d) * H0 + h]);
    }
    scratch[tid] = s;
  }
  // M_b^T -> LDS (fp16, [h][d])
  #pragma unroll 4
  for (int i = 0; i < 32; ++i) {
    int idx = i * 256 + tid;
    int h = idx & 127, d = idx >> 7;
    float val = W0[(64 + d) * H0 + h] - W0[(128 + d) * H0 + h]
              + qb[d] * W0[(192 + d) * H0 + h];
    MhT[h * MP + d] = (_Float16)val;
  }
  // W1^T -> LDS (fp16, [j][h])
  #pragma unroll 4
  for (int i = 0; i < 32; ++i) {
    int idx = i * 256 + tid;
    int hh = idx >> 6, j = idx & 63;
    W1T[j * WP + hh] = (_Float16)W1[idx];
  }
  if (tid < DD) WfS[tid] = Wf[tid];
  __syncthreads();
  if (tid < H0) {
    float cbv = scratch[tid] + scratch[tid + 128] + b0[tid];
    _Float16 chi = (_Float16)cbv;
    MhT[tid * MP + 64] = chi;
    MhT[tid * MP + 65] = (_Float16)(cbv - (float)chi);
  }
  if (tid < H1) {
    float bb = b1[tid];
    _Float16 bh = (_Float16)bb;
    W1T[tid * WP + 128] = bh;
    W1T[tid * WP + 129] = (_Float16)(bb - (float)bh);
  }
  __syncthreads();

  float m_run = -1e30f, s_run = 0.f, o_run = 0.f;

  for (int s = wid; s < 13; s += 4) {
    const int t0   = s * 16;
    const int trow = t0 + r16;
    const bool tv  = trow < TT;

    int mm = tv ? mb[trow] : -1;

    // k^T B-fragments straight from global; v stream issued early
    float4 kq[4];
    #pragma unroll
    for (int ks = 0; ks < 4; ++ks) {
      float4 z = {0.f, 0.f, 0.f, 0.f};
      kq[ks] = tv ? *(const float4*)(kb + trow * DD + ks * 16 + 4 * g4) : z;
    }
    float vv[16];
    #pragma unroll
    for (int i = 0; i < 16; ++i) {
      int t = t0 + i;
      vv[i] = (t < TT) ? vb[t * DD + lane] : 0.f;
    }

    // hi/lo split of k (B operand)
    f16x4 bhi[4], blo[4];
    #pragma unroll
    for (int ks = 0; ks < 4; ++ks) {
      float kf[4] = {kq[ks].x, kq[ks].y, kq[ks].z, kq[ks].w};
      #pragma unroll
      for (int j = 0; j < 4; ++j) {
        _Float16 hi = (_Float16)kf[j];
        bhi[ks][j] = hi;
        blo[ks][j] = (_Float16)(kf[j] - (float)hi);
      }
    }
    // constant-1 B fragment for the bias K-rows (valid t cols only)
    f16x4 bONE = {(_Float16)0.f, (_Float16)0.f, (_Float16)0.f, (_Float16)0.f};
    if (g4 == 0 && tv) { bONE[0] = (_Float16)1.f; bONE[1] = (_Float16)1.f; }

    // ---- layer0^T: h0t[h=c*16+4g4+r][t=t0+r16], bias folded, relu, hi/lo split ----
    f16x4 hhi[8], hlo[8];
    #pragma unroll
    for (int c = 0; c < 8; ++c) {
      const _Float16* mrow = &MhT[(c * 16 + r16) * MP];
      f32x4 acc = {0.f, 0.f, 0.f, 0.f};
      #pragma unroll
      for (int ks = 0; ks < 4; ++ks) {
        f16x4 af = *(const f16x4*)(mrow + ks * 16 + 4 * g4);
        acc = __builtin_amdgcn_mfma_f32_16x16x16f16(af, bhi[ks], acc, 0, 0, 0);
        acc = __builtin_amdgcn_mfma_f32_16x16x16f16(af, blo[ks], acc, 0, 0, 0);
      }
      f16x4 ab = {(_Float16)0.f, (_Float16)0.f, (_Float16)0.f, (_Float16)0.f};
      if (g4 == 0) { ab[0] = mrow[64]; ab[1] = mrow[65]; }
      acc = __builtin_amdgcn_mfma_f32_16x16x16f16(ab, bONE, acc, 0, 0, 0);
      #pragma unroll
      for (int r = 0; r < 4; ++r) {
        float hv = acc[r] > 0.f ? acc[r] : 0.f;
        _Float16 hi = (_Float16)hv;
        hhi[c][r] = hi;
        hlo[c][r] = (_Float16)(hv - (float)hi);
      }
    }

    // ---- layer1^T + logit: h1t[j=c1*16+4g4+r][t], b1 folded ----
    float p = 0.f;
    #pragma unroll
    for (int c1 = 0; c1 < 4; ++c1) {
      const _Float16* wrow = &W1T[(c1 * 16 + r16) * WP];
      f32x4 acc = {0.f, 0.f, 0.f, 0.f};
      #pragma unroll
      for (int ks = 0; ks < 8; ++ks) {
        f16x4 af = *(const f16x4*)(wrow + ks * 16 + 4 * g4);
        acc = __builtin_amdgcn_mfma_f32_16x16x16f16(af, hhi[ks], acc, 0, 0, 0);
        acc = __builtin_amdgcn_mfma_f32_16x16x16f16(af, hlo[ks], acc, 0, 0, 0);
      }
      f16x4 ab = {(_Float16)0.f, (_Float16)0.f, (_Float16)0.f, (_Float16)0.f};
      if (g4 == 0) { ab[0] = wrow[128]; ab[1] = wrow[129]; }
      acc = __builtin_amdgcn_mfma_f32_16x16x16f16(ab, bONE, acc, 0, 0, 0);
      f32x4 wf4 = *(const f32x4*)(&WfS[c1 * 16 + 4 * g4]);
      #pragma unroll
      for (int r = 0; r < 4; ++r) {
        float h1 = acc[r] > 0.f ? acc[r] : 0.f;
        p = fmaf(h1, wf4[r], p);
      }
    }

    // reduce logit over the 4 g4 replicas (same t-col)
    p += __shfl_xor(p, 16, 64);
    p += __shfl_xor(p, 32, 64);
    // mask: keep / masked(-1e30) / pad(-2e30)
    p = (mm == 1) ? p : (mm == 0 ? -1e30f : -2e30f);

    // gather the strip's 16 logits to every lane
    float lt[16];
    #pragma unroll
    for (int i = 0; i < 16; ++i) lt[i] = __shfl(p, i, 64);

    // online softmax update + v pooling (d = lane)
    float m_new = m_run;
    #pragma unroll
    for (int i = 0; i < 16; ++i) m_new = fmaxf(m_new, lt[i]);
    float scale = __expf(m_run - m_new);
    float e[16];
    float esum = 0.f;
    #pragma unroll
    for (int i = 0; i < 16; ++i) { e[i] = __expf(lt[i] - m_new); esum += e[i]; }
    s_run = s_run * scale + esum;
    o_run *= scale;
    #pragma unroll
    for (int i = 0; i < 16; ++i) o_run = fmaf(e[i], vv[i], o_run);
    m_run = m_new;
  }

  // ---- cross-wave flash combine (scratch reused: owav[4][68] @0, msh @272, ssh @276) ----
  scratch[wid * 68 + lane] = o_run;
  if (lane == 0) { scratch[272 + wid] = m_run; scratch[276 + wid] = s_run; }
  __syncthreads();

  if (tid < DD) {
    float mstar = fmaxf(fmaxf(scratch[272], scratch[273]),
                        fmaxf(scratch[274], scratch[275]));
    float acc = 0.f, ssum = 0.f;
    #pragma unroll
    for (int w = 0; w < 4; ++w) {
      float f = __expf(scratch[272 + w] - mstar);
      acc  += scratch[w * 68 + tid] * f;
      ssum += scratch[276 + w] * f;
    }
    out[b * DD + tid] = acc / ssum;
  }
}

extern "C" void kernel_launch(void* const* d_in, const int* in_sizes, int n_in,
                              void* d_out, int out_size, void* d_ws, size_t ws_size,
                              hipStream_t stream) {
  const float* q    = (const float*)d_in[0];
  const float* k    = (const float*)d_in[1];
  const float* v    = (const float*)d_in[2];
  const int*   mask = (const int*)d_in[3];
  const float* W0   = (const float*)d_in[4];
  const float* b0   = (const float*)d_in[5];
  const float* W1   = (const float*)d_in[6];
  const float* b1   = (const float*)d_in[7];
  const float* Wf   = (const float*)d_in[8];
  float* out = (float*)d_out;
  din_attn<<<dim3(NB), dim3(256), 0, stream>>>(q, k, v, mask, W0, b0, W1, b1, Wf, out);
}